// Round 1
// baseline (3415.794 us; speedup 1.0000x reference)
//
#include <hip/hip_runtime.h>

#define TT 2048
#define DD 1024
#define ND3 3072
#define LL 4
#define MAXIT 16

__device__ __forceinline__ float sigmoidf_(float x) { return 1.f / (1.f + __expf(-x)); }

__device__ __forceinline__ float gru_out(float xr, float xz, float xn,
                                         float hr, float hz, float hn, float hp)
{
    float rg = sigmoidf_(xr + hr);
    float zg = sigmoidf_(xz + hz);
    float ng = tanhf(xn + rg * hn);
    return (1.f - zg) * ng + zg * hp;
}

// ---------------------------------------------------------------------------
// Episode segmentation + counting sort (descending length). One block.
// Outputs: g_start[e], g_len[e], g_perm[r] (episodes sorted by len desc),
// g_nact[i] = #{episodes with len > i} for i=0..MAXIT  (g_nact[0] = n_ep).
// ---------------------------------------------------------------------------
__global__ __launch_bounds__(256)
void seg_kernel(const int* __restrict__ term, int* __restrict__ g_start,
                int* __restrict__ g_len, int* __restrict__ g_perm,
                int* __restrict__ g_nact)
{
    __shared__ int s_term[TT];
    __shared__ int s_start[TT];
    __shared__ int s_len[TT];
    __shared__ int s_hist[TT + 1];
    __shared__ int s_n;
    int tid = threadIdx.x;
    for (int t = tid; t < TT; t += 256) s_term[t] = term[t];
    for (int t = tid; t < TT + 1; t += 256) s_hist[t] = 0;
    __syncthreads();
    if (tid == 0) {
        int n = 0;
        for (int t = 0; t < TT; ++t) {
            if (t == 0 || s_term[t] != 0) {
                if (n > 0) s_len[n - 1] = t - s_start[n - 1];
                s_start[n] = t;
                ++n;
            }
        }
        s_len[n - 1] = TT - s_start[n - 1];
        s_n = n;
        for (int e = 0; e < n; ++e) s_hist[s_len[e]]++;
        // transform: s_hist[L] := #{len > L}
        int cum = 0;
        for (int L = TT; L >= 1; --L) { int h = s_hist[L]; s_hist[L] = cum; cum += h; }
        g_nact[0] = n;
        for (int i = 1; i <= MAXIT; ++i) g_nact[i] = s_hist[i];
        // stable scatter into descending-length order
        for (int e = 0; e < n; ++e) { int l = s_len[e]; g_perm[s_hist[l]++] = e; }
    }
    __syncthreads();
    int n = s_n;
    for (int t = tid; t < n; t += 256) { g_start[t] = s_start[t]; g_len[t] = s_len[t]; }
}

// ---------------------------------------------------------------------------
// Phase A: C[2048][3072] = Y[2048][1024] @ W[1024][3072]   (fp32 tiled)
// ---------------------------------------------------------------------------
__global__ __launch_bounds__(256)
void gemm_in(const float* __restrict__ Y, const float* __restrict__ W,
             float* __restrict__ C)
{
    __shared__ __align__(16) float As[16][68];   // [kk][m], padded
    __shared__ __align__(16) float Bs[16][64];   // [kk][n]
    int tid = threadIdx.x;
    int n0 = blockIdx.x * 64;
    int m0 = blockIdx.y * 64;
    int tx = tid & 15, ty = tid >> 4;
    float acc[4][4] = {};
    for (int k0 = 0; k0 < DD; k0 += 16) {
#pragma unroll
        for (int i = 0; i < 4; ++i) {
            int idx = i * 256 + tid;
            int m = idx >> 4, kk = idx & 15;
            As[kk][m] = Y[(size_t)(m0 + m) * DD + k0 + kk];
        }
#pragma unroll
        for (int i = 0; i < 4; ++i) {
            int idx = i * 256 + tid;
            int nn = idx & 63, kk = idx >> 6;
            Bs[kk][nn] = W[(size_t)(k0 + kk) * ND3 + n0 + nn];
        }
        __syncthreads();
#pragma unroll
        for (int kk = 0; kk < 16; ++kk) {
            float4 a = *(const float4*)&As[kk][ty * 4];
            float4 b = *(const float4*)&Bs[kk][tx * 4];
            acc[0][0] += a.x * b.x; acc[0][1] += a.x * b.y; acc[0][2] += a.x * b.z; acc[0][3] += a.x * b.w;
            acc[1][0] += a.y * b.x; acc[1][1] += a.y * b.y; acc[1][2] += a.y * b.z; acc[1][3] += a.y * b.w;
            acc[2][0] += a.z * b.x; acc[2][1] += a.z * b.y; acc[2][2] += a.z * b.z; acc[2][3] += a.z * b.w;
            acc[3][0] += a.w * b.x; acc[3][1] += a.w * b.y; acc[3][2] += a.w * b.z; acc[3][3] += a.w * b.w;
        }
        __syncthreads();
    }
#pragma unroll
    for (int i = 0; i < 4; ++i) {
        float4 v = make_float4(acc[i][0], acc[i][1], acc[i][2], acc[i][3]);
        *(float4*)&C[(size_t)(m0 + ty * 4 + i) * ND3 + n0 + tx * 4] = v;
    }
}

// ---------------------------------------------------------------------------
// Iteration 0: h_in = 0 (or last_states for the t==0 episode) -> elementwise,
// with a generic GEMV fallback if last_states is nonzero.
// Writes Hbuf0 and y.
// ---------------------------------------------------------------------------
__global__ __launch_bounds__(256)
void it0_kernel(const float* __restrict__ xp, const float* __restrict__ Wh,
                const float* __restrict__ bh, const float* __restrict__ h0g,
                const int* __restrict__ term, float* __restrict__ Hnext,
                float* __restrict__ yout, const int* __restrict__ g_start,
                const int* __restrict__ g_perm, const int* __restrict__ g_nact)
{
    int M = g_nact[0];
    int r = blockIdx.x;
    if (r >= M) return;
    int e = g_perm[r];
    int t = g_start[e];
    int tid = threadIdx.x;
    bool useh0 = (t == 0) && (term[0] == 0);
    __shared__ float h0s[DD];
    __shared__ int s_nz;
    if (tid == 0) s_nz = 0;
    __syncthreads();
    if (useh0) {
        int nz = 0;
#pragma unroll
        for (int j = 0; j < 4; ++j) {
            float v = h0g[tid + j * 256];
            h0s[tid + j * 256] = v;
            nz |= (v != 0.f) ? 1 : 0;
        }
        if (nz) atomicOr(&s_nz, 1);
    }
    __syncthreads();
    bool gemv = useh0 && (s_nz != 0);
#pragma unroll
    for (int j = 0; j < 4; ++j) {
        int c = tid + j * 256;
        float hr = bh[c], hz = bh[DD + c], hn = bh[2 * DD + c];
        if (gemv) {
            for (int k = 0; k < DD; ++k) {
                float hv = h0s[k];
                hr += hv * Wh[(size_t)k * ND3 + c];
                hz += hv * Wh[(size_t)k * ND3 + DD + c];
                hn += hv * Wh[(size_t)k * ND3 + 2 * DD + c];
            }
        }
        float hp = useh0 ? h0s[c] : 0.f;
        float xr = xp[(size_t)t * ND3 + c];
        float xz = xp[(size_t)t * ND3 + DD + c];
        float xn = xp[(size_t)t * ND3 + 2 * DD + c];
        float hnew = gru_out(xr, xz, xn, hr, hz, hn, hp);
        Hnext[(size_t)e * DD + c] = hnew;
        yout[(size_t)t * DD + c] = hnew;
    }
}

// ---------------------------------------------------------------------------
// Iteration i>=1: hp = H_active @ Wh + bh, fused gates + state update.
// Block: 16 rows x (64 cols x 3 gate slices). Active rows are the prefix
// [0, n_act[i]) of the sorted episode order.
// ---------------------------------------------------------------------------
__global__ __launch_bounds__(256)
void iter_kernel(int it, const float* __restrict__ Hprev, float* __restrict__ Hnext,
                 const float* __restrict__ xp, const float* __restrict__ Wh,
                 const float* __restrict__ bh, float* __restrict__ yout,
                 const int* __restrict__ g_start, const int* __restrict__ g_perm,
                 const int* __restrict__ g_nact)
{
    int M = g_nact[it];
    int r0 = blockIdx.y * 16;
    if (r0 >= M) return;
    int c0 = blockIdx.x * 64;
    __shared__ __align__(16) float Hs[32][20];      // [kk][row], padded
    __shared__ __align__(16) float Bs[3][32][64];   // [slice][kk][n]
    __shared__ int s_e[16], s_t[16], s_v[16];
    int tid = threadIdx.x;
    if (tid < 16) {
        int r = r0 + tid;
        int v = (r < M) ? 1 : 0;
        int e = v ? g_perm[r] : 0;
        s_e[tid] = e;
        s_v[tid] = v;
        s_t[tid] = v ? (g_start[e] + it) : 0;
    }
    __syncthreads();
    int tx = tid & 63, tyg = tid >> 6;   // thread covers rows 4*tyg..4*tyg+3, col c0+tx
    float acc[3][4] = {};
    for (int k0 = 0; k0 < DD; k0 += 32) {
#pragma unroll
        for (int i = 0; i < 2; ++i) {
            int idx = i * 256 + tid;
            int row = idx >> 5, kk = idx & 31;
            float v = s_v[row] ? Hprev[(size_t)s_e[row] * DD + k0 + kk] : 0.f;
            Hs[kk][row] = v;
        }
#pragma unroll
        for (int i = 0; i < 24; ++i) {
            int idx = i * 256 + tid;
            int nn = idx & 63, kk = (idx >> 6) & 31, s = idx >> 11;
            Bs[s][kk][nn] = Wh[(size_t)(k0 + kk) * ND3 + s * DD + c0 + nn];
        }
        __syncthreads();
#pragma unroll
        for (int kk = 0; kk < 32; ++kk) {
            float4 av = *(const float4*)&Hs[kk][tyg * 4];
            float b0 = Bs[0][kk][tx];
            float b1 = Bs[1][kk][tx];
            float b2 = Bs[2][kk][tx];
            acc[0][0] += av.x * b0; acc[0][1] += av.y * b0; acc[0][2] += av.z * b0; acc[0][3] += av.w * b0;
            acc[1][0] += av.x * b1; acc[1][1] += av.y * b1; acc[1][2] += av.z * b1; acc[1][3] += av.w * b1;
            acc[2][0] += av.x * b2; acc[2][1] += av.y * b2; acc[2][2] += av.z * b2; acc[2][3] += av.w * b2;
        }
        __syncthreads();
    }
#pragma unroll
    for (int j = 0; j < 4; ++j) {
        int lr = tyg * 4 + j;
        if (!s_v[lr]) continue;
        int e = s_e[lr], t = s_t[lr];
        int c = c0 + tx;
        float hr = acc[0][j] + bh[c];
        float hz = acc[1][j] + bh[DD + c];
        float hn = acc[2][j] + bh[2 * DD + c];
        float xr = xp[(size_t)t * ND3 + c];
        float xz = xp[(size_t)t * ND3 + DD + c];
        float xn = xp[(size_t)t * ND3 + 2 * DD + c];
        float hp = Hprev[(size_t)e * DD + c];
        float hnew = gru_out(xr, xz, xn, hr, hz, hn, hp);
        Hnext[(size_t)e * DD + c] = hnew;
        yout[(size_t)t * DD + c] = hnew;
    }
}

// ---------------------------------------------------------------------------
// Cleanup: serially finish any episode with len > MAXIT (normally none).
// ---------------------------------------------------------------------------
__global__ __launch_bounds__(256)
void cleanup_kernel(const float* __restrict__ Hlast, const float* __restrict__ xp,
                    const float* __restrict__ Wh, const float* __restrict__ bh,
                    float* __restrict__ yout, const int* __restrict__ g_start,
                    const int* __restrict__ g_len, const int* __restrict__ g_perm,
                    const int* __restrict__ g_nact)
{
    int Mt = g_nact[MAXIT];
    if (Mt == 0) return;
    __shared__ float h[DD];
    int tid = threadIdx.x;
    for (int r = blockIdx.x; r < Mt; r += gridDim.x) {
        int e = g_perm[r];
        int s0 = g_start[e];
        int L = g_len[e];
#pragma unroll
        for (int j = 0; j < 4; ++j) h[tid + j * 256] = Hlast[(size_t)e * DD + tid + j * 256];
        __syncthreads();
        for (int i = MAXIT; i < L; ++i) {
            int t = s0 + i;
            float hnew[4];
#pragma unroll
            for (int j = 0; j < 4; ++j) {
                int c = tid + j * 256;
                float hr = bh[c], hz = bh[DD + c], hn = bh[2 * DD + c];
                for (int k = 0; k < DD; ++k) {
                    float hv = h[k];
                    hr += hv * Wh[(size_t)k * ND3 + c];
                    hz += hv * Wh[(size_t)k * ND3 + DD + c];
                    hn += hv * Wh[(size_t)k * ND3 + 2 * DD + c];
                }
                float xr = xp[(size_t)t * ND3 + c];
                float xz = xp[(size_t)t * ND3 + DD + c];
                float xn = xp[(size_t)t * ND3 + 2 * DD + c];
                float hp = h[c];
                hnew[j] = gru_out(xr, xz, xn, hr, hz, hn, hp);
                yout[(size_t)t * DD + c] = hnew[j];
            }
            __syncthreads();
#pragma unroll
            for (int j = 0; j < 4; ++j) h[tid + j * 256] = hnew[j];
            __syncthreads();
        }
        __syncthreads();
    }
}

__global__ __launch_bounds__(256)
void finals_kernel(const float* __restrict__ y, float* __restrict__ dst)
{
    int tid = threadIdx.x;
#pragma unroll
    for (int j = 0; j < 4; ++j)
        dst[tid + j * 256] = y[(size_t)(TT - 1) * DD + tid + j * 256];
}

// ---------------------------------------------------------------------------
extern "C" void kernel_launch(void* const* d_in, const int* in_sizes, int n_in,
                              void* d_out, int out_size, void* d_ws, size_t ws_size,
                              hipStream_t stream)
{
    const float* x_in = (const float*)d_in[0];
    const int*   term = (const int*)d_in[1];
    const float* h0   = (const float*)d_in[2];   // (L, D)
    const float* Wi   = (const float*)d_in[3];   // (L, D, 3D)
    const float* Wh   = (const float*)d_in[4];   // (L, D, 3D)
    const float* bh   = (const float*)d_in[5];   // (L, 3D)
    float* out = (float*)d_out;

    float* wsf = (float*)d_ws;
    float* xp  = wsf;                               // TT*ND3
    float* Hb0 = xp + (size_t)TT * ND3;             // TT*DD
    float* Hb1 = Hb0 + (size_t)TT * DD;             // TT*DD
    float* yA  = Hb1 + (size_t)TT * DD;             // TT*DD
    float* yB  = yA + (size_t)TT * DD;              // TT*DD
    int* ib      = (int*)(yB + (size_t)TT * DD);
    int* g_start = ib;              // TT
    int* g_len   = ib + TT;         // TT
    int* g_perm  = ib + 2 * TT;     // TT
    int* g_nact  = ib + 3 * TT;     // MAXIT+1

    seg_kernel<<<1, 256, 0, stream>>>(term, g_start, g_len, g_perm, g_nact);

    const float* Ys[4] = { x_in, yA, yB, yA };
    float*       Yo[4] = { yA, yB, yA, out };

    for (int l = 0; l < LL; ++l) {
        const float* Wil = Wi + (size_t)l * DD * ND3;
        const float* Whl = Wh + (size_t)l * DD * ND3;
        const float* bhl = bh + (size_t)l * ND3;

        gemm_in<<<dim3(ND3 / 64, TT / 64), 256, 0, stream>>>(Ys[l], Wil, xp);

        it0_kernel<<<TT, 256, 0, stream>>>(xp, Whl, bhl, h0 + (size_t)l * DD, term,
                                           Hb0, Yo[l], g_start, g_perm, g_nact);

        for (int it = 1; it < MAXIT; ++it) {
            float* Hp = (it & 1) ? Hb0 : Hb1;   // Hbuf[(it-1)&1]
            float* Hn = (it & 1) ? Hb1 : Hb0;   // Hbuf[it&1]
            int maxrows = TT / (it + 1);        // n_act[it] <= TT/(it+1)
            dim3 g(DD / 64, (maxrows + 15) / 16);
            iter_kernel<<<g, 256, 0, stream>>>(it, Hp, Hn, xp, Whl, bhl, Yo[l],
                                               g_start, g_perm, g_nact);
        }

        float* Hlast = ((MAXIT - 1) & 1) ? Hb1 : Hb0;
        cleanup_kernel<<<64, 256, 0, stream>>>(Hlast, xp, Whl, bhl, Yo[l],
                                               g_start, g_len, g_perm, g_nact);

        finals_kernel<<<1, 256, 0, stream>>>(Yo[l], out + (size_t)TT * DD + (size_t)l * DD);
    }
}

// Round 2
// 2611.565 us; speedup vs baseline: 1.3079x; 1.3079x over previous
//
#include <hip/hip_runtime.h>

#define TT 2048
#define DD 1024
#define ND3 3072
#define LL 4
#define MAXIT 16

typedef float f32x4 __attribute__((ext_vector_type(4)));
typedef __bf16 bf16x8 __attribute__((ext_vector_type(8)));

__device__ __forceinline__ float sigmoidf_(float x) { return 1.f / (1.f + __expf(-x)); }

__device__ __forceinline__ float gru_out(float xr, float xz, float xn,
                                         float hr, float hz, float hn, float hp)
{
    float rg = sigmoidf_(xr + hr);
    float zg = sigmoidf_(xz + hz);
    float ng = tanhf(xn + rg * hn);
    return (1.f - zg) * ng + zg * hp;
}

__device__ __forceinline__ ushort f2bf(float x)
{
    unsigned u = __builtin_bit_cast(unsigned, x);
    return (ushort)((u + 0x7FFFu + ((u >> 16) & 1u)) >> 16);
}

__device__ __forceinline__ void gld_lds16(const void* g, void* l)
{
    __builtin_amdgcn_global_load_lds(
        (const __attribute__((address_space(1))) unsigned int*)g,
        (__attribute__((address_space(3))) unsigned int*)l, 16, 0, 0);
}

// ---------------------------------------------------------------------------
// Episode segmentation + counting sort (descending length). One block, parallel.
// g_nact[i] = #{episodes with len > i}, i=0..MAXIT (g_nact[0] = n_ep).
// ---------------------------------------------------------------------------
__global__ __launch_bounds__(256)
void seg_kernel(const int* __restrict__ term, int* __restrict__ g_start,
                int* __restrict__ g_len, int* __restrict__ g_perm,
                int* __restrict__ g_nact)
{
    __shared__ int s_start[TT + 1];
    __shared__ int s_len[TT];
    __shared__ int s_hist[TT + 1];
    __shared__ int s_base[TT + 1];
    __shared__ int s_p[256];
    __shared__ int s_wsum[33];
    __shared__ int s_n;
    int tid = threadIdx.x, lane = tid & 63, wv = tid >> 6;

    for (int i = tid; i <= TT; i += 256) s_hist[i] = 0;

    unsigned long long msk[8];
#pragma unroll
    for (int p = 0; p < 8; ++p) {
        int t = p * 256 + tid;
        int bit = (t == 0) || (term[t] != 0);
        unsigned long long m = __ballot(bit);
        msk[p] = m;
        if (lane == 0) s_wsum[p * 4 + wv] = __popcll(m);
    }
    __syncthreads();
    if (tid == 0) {
        int run = 0;
        for (int i = 0; i < 32; ++i) { int v = s_wsum[i]; s_wsum[i] = run; run += v; }
        s_n = run;
    }
    __syncthreads();
    int n = s_n;
#pragma unroll
    for (int p = 0; p < 8; ++p) {
        int t = p * 256 + tid;
        unsigned long long m = msk[p];
        if ((m >> lane) & 1ull) {
            int e = s_wsum[p * 4 + wv] + __popcll(m & ((1ull << lane) - 1ull));
            s_start[e] = t;
        }
    }
    if (tid == 0) s_start[n] = TT;
    __syncthreads();
    for (int e = tid; e < n; e += 256) {
        int L = s_start[e + 1] - s_start[e];
        s_len[e] = L;
        atomicAdd(&s_hist[L], 1);
    }
    __syncthreads();
    // suffix sums: s_base[L] = #{len > L} for L=1..TT (two-level scan)
    int lo = 8 * tid + 1;
    int p_i = 0;
#pragma unroll
    for (int j = 0; j < 8; ++j) p_i += s_hist[lo + j];
    s_p[tid] = p_i;
    __syncthreads();
    if (tid < 64) {
        int q0 = s_p[tid * 4], q1 = s_p[tid * 4 + 1], q2 = s_p[tid * 4 + 2], q3 = s_p[tid * 4 + 3];
        int q = q0 + q1 + q2 + q3;
        int acc = q;
        for (int off = 1; off < 64; off <<= 1) {
            int v = __shfl_down(acc, off);
            if (lane + off < 64) acc += v;
        }
        int ex = acc - q;   // sum over lanes > lane
        s_p[tid * 4 + 3] = ex;
        s_p[tid * 4 + 2] = ex + q3;
        s_p[tid * 4 + 1] = ex + q3 + q2;
        s_p[tid * 4 + 0] = ex + q3 + q2 + q1;
    }
    __syncthreads();
    int running = s_p[tid];
    for (int j = 7; j >= 0; --j) {
        s_base[lo + j] = running;
        running += s_hist[lo + j];
    }
    __syncthreads();
    if (tid == 0) g_nact[0] = n;
    if (tid >= 1 && tid <= MAXIT) g_nact[tid] = s_base[tid];
    __syncthreads();
    for (int e = tid; e < n; e += 256) {
        g_start[e] = s_start[e];
        int L = s_len[e];
        g_len[e] = L;
        int pos = atomicAdd(&s_base[L], 1);
        g_perm[pos] = e;
    }
}

// ---------------------------------------------------------------------------
// fp32 -> bf16 cast (vectorized), n multiple of 4
// ---------------------------------------------------------------------------
__global__ __launch_bounds__(256)
void cast_bf(const float* __restrict__ src, ushort* __restrict__ dst, int n)
{
    int base = (blockIdx.x * 256 + threadIdx.x) * 4;
    if (base < n) {
        float4 v = *(const float4*)(src + base);
        ushort4 o;
        o.x = f2bf(v.x); o.y = f2bf(v.y); o.z = f2bf(v.z); o.w = f2bf(v.w);
        *(ushort4*)(dst + base) = o;
    }
}

// ---------------------------------------------------------------------------
// Transpose + cast one weight matrix: src [DD][ND3] fp32 -> dst [ND3][DD] bf16
// ---------------------------------------------------------------------------
__global__ __launch_bounds__(256)
void transcast(const float* __restrict__ src, ushort* __restrict__ dst)
{
    __shared__ float tile[64][65];
    int tid = threadIdx.x;
    int n0 = blockIdx.x * 64, k0 = blockIdx.y * 64;
#pragma unroll
    for (int i = 0; i < 16; ++i) {
        int idx = i * 256 + tid;
        int r = idx >> 6, c = idx & 63;
        tile[r][c] = src[(size_t)(k0 + r) * ND3 + n0 + c];
    }
    __syncthreads();
#pragma unroll
    for (int i = 0; i < 8; ++i) {
        int idx = i * 256 + tid;
        int nr = idx >> 5, kp = idx & 31;
        float a = tile[kp * 2][nr], b = tile[kp * 2 + 1][nr];
        unsigned pa = (unsigned)f2bf(a) | ((unsigned)f2bf(b) << 16);
        *(unsigned*)&dst[(size_t)(n0 + nr) * DD + k0 + kp * 2] = pa;
    }
}

// ---------------------------------------------------------------------------
// Phase A GEMM (bf16 MFMA): C[2048][3072] = A[2048][1024] * BT[3072][1024]^T
// 128x128 tile, 4 waves (2x2), BK=32, global_load_lds staging, XOR k-slot swizzle.
// ---------------------------------------------------------------------------
__global__ __launch_bounds__(256)
void gemm_mfma(const ushort* __restrict__ A, const ushort* __restrict__ BT,
               float* __restrict__ C)
{
    __shared__ ushort As[128 * 32];
    __shared__ ushort Bs[128 * 32];
    int tid = threadIdx.x, lane = tid & 63, wv = tid >> 6;
    int m0 = blockIdx.y * 128, n0 = blockIdx.x * 128;
    int wr = wv >> 1, wc = wv & 1;
    f32x4 acc[4][4] = {};

    // staging: pass p covers 16B chunk ci = p*256+tid; row = ci>>2, slot = ci&3
    int ci0 = tid, ci1 = 256 + tid;
    int r0s = ci0 >> 2, r1s = ci1 >> 2;
    int ss0 = (ci0 & 3) ^ ((r0s >> 1) & 3);
    int ss1 = (ci1 & 3) ^ ((r1s >> 1) & 3);
    const ushort* Ar0 = A + (size_t)(m0 + r0s) * DD + ss0 * 8;
    const ushort* Ar1 = A + (size_t)(m0 + r1s) * DD + ss1 * 8;
    const ushort* Br0 = BT + (size_t)(n0 + r0s) * DD + ss0 * 8;
    const ushort* Br1 = BT + (size_t)(n0 + r1s) * DD + ss1 * 8;

    int g = lane >> 4, fr = lane & 15;

    for (int k0 = 0; k0 < DD; k0 += 32) {
        gld_lds16(Ar0 + k0, (char*)As + wv * 1024);
        gld_lds16(Ar1 + k0, (char*)As + 4096 + wv * 1024);
        gld_lds16(Br0 + k0, (char*)Bs + wv * 1024);
        gld_lds16(Br1 + k0, (char*)Bs + 4096 + wv * 1024);
        __syncthreads();

        bf16x8 af[4], bb[4];
#pragma unroll
        for (int mi = 0; mi < 4; ++mi) {
            int row = wr * 64 + mi * 16 + fr;
            int slot = g ^ ((row >> 1) & 3);
            af[mi] = *(const bf16x8*)(As + row * 32 + slot * 8);
        }
#pragma unroll
        for (int ni = 0; ni < 4; ++ni) {
            int row = wc * 64 + ni * 16 + fr;
            int slot = g ^ ((row >> 1) & 3);
            bb[ni] = *(const bf16x8*)(Bs + row * 32 + slot * 8);
        }
#pragma unroll
        for (int mi = 0; mi < 4; ++mi)
#pragma unroll
            for (int ni = 0; ni < 4; ++ni)
                acc[mi][ni] = __builtin_amdgcn_mfma_f32_16x16x32_bf16(
                    af[mi], bb[ni], acc[mi][ni], 0, 0, 0);
        __syncthreads();
    }

    int orow = (lane >> 4) * 4, ocol = lane & 15;
#pragma unroll
    for (int mi = 0; mi < 4; ++mi)
#pragma unroll
        for (int ni = 0; ni < 4; ++ni)
#pragma unroll
            for (int r2 = 0; r2 < 4; ++r2)
                C[(size_t)(m0 + wr * 64 + mi * 16 + orow + r2) * ND3 +
                  n0 + wc * 64 + ni * 16 + ocol] = acc[mi][ni][r2];
}

// ---------------------------------------------------------------------------
// Iteration 0: h_in = 0 (or last_states for the t==0 episode).
// ---------------------------------------------------------------------------
__global__ __launch_bounds__(256)
void it0_kernel(const float* __restrict__ xp, const float* __restrict__ Wh,
                const float* __restrict__ bh, const float* __restrict__ h0g,
                const int* __restrict__ term, float* __restrict__ Hnext,
                ushort* __restrict__ ybf, float* __restrict__ yf32,
                float* __restrict__ finals, const int* __restrict__ g_start,
                const int* __restrict__ g_perm, const int* __restrict__ g_nact)
{
    int M = g_nact[0];
    int r = blockIdx.x;
    if (r >= M) return;
    int e = g_perm[r];
    int t = g_start[e];
    int tid = threadIdx.x;
    bool useh0 = (t == 0) && (term[0] == 0);
    __shared__ float h0s[DD];
    __shared__ int s_nz;
    if (tid == 0) s_nz = 0;
    __syncthreads();
    if (useh0) {
        int nz = 0;
#pragma unroll
        for (int j = 0; j < 4; ++j) {
            float v = h0g[tid + j * 256];
            h0s[tid + j * 256] = v;
            nz |= (v != 0.f) ? 1 : 0;
        }
        if (nz) atomicOr(&s_nz, 1);
    }
    __syncthreads();
    bool gemv = useh0 && (s_nz != 0);
#pragma unroll
    for (int j = 0; j < 4; ++j) {
        int c = tid + j * 256;
        float hr = bh[c], hz = bh[DD + c], hn = bh[2 * DD + c];
        if (gemv) {
            for (int k = 0; k < DD; ++k) {
                float hv = h0s[k];
                hr += hv * Wh[(size_t)k * ND3 + c];
                hz += hv * Wh[(size_t)k * ND3 + DD + c];
                hn += hv * Wh[(size_t)k * ND3 + 2 * DD + c];
            }
        }
        float hp = useh0 ? h0s[c] : 0.f;
        float xr = xp[(size_t)t * ND3 + c];
        float xz = xp[(size_t)t * ND3 + DD + c];
        float xn = xp[(size_t)t * ND3 + 2 * DD + c];
        float hnew = gru_out(xr, xz, xn, hr, hz, hn, hp);
        Hnext[(size_t)e * DD + c] = hnew;
        if (yf32) yf32[(size_t)t * DD + c] = hnew;
        else      ybf[(size_t)t * DD + c] = f2bf(hnew);
        if (t == TT - 1) finals[c] = hnew;
    }
}

// ---------------------------------------------------------------------------
// Iteration i>=1: hp = H_active @ Wh + bh, fused gates + state update. fp32.
// ---------------------------------------------------------------------------
__global__ __launch_bounds__(256)
void iter_kernel(int it, const float* __restrict__ Hprev, float* __restrict__ Hnext,
                 const float* __restrict__ xp, const float* __restrict__ Wh,
                 const float* __restrict__ bh, ushort* __restrict__ ybf,
                 float* __restrict__ yf32, float* __restrict__ finals,
                 const int* __restrict__ g_start, const int* __restrict__ g_perm,
                 const int* __restrict__ g_nact)
{
    int M = g_nact[it];
    int r0 = blockIdx.y * 16;
    if (r0 >= M) return;
    int c0 = blockIdx.x * 64;
    __shared__ __align__(16) float Hs[32][20];
    __shared__ __align__(16) float Bs[3][32][64];
    __shared__ int s_e[16], s_t[16], s_v[16];
    int tid = threadIdx.x;
    if (tid < 16) {
        int r = r0 + tid;
        int v = (r < M) ? 1 : 0;
        int e = v ? g_perm[r] : 0;
        s_e[tid] = e;
        s_v[tid] = v;
        s_t[tid] = v ? (g_start[e] + it) : 0;
    }
    __syncthreads();
    int tx = tid & 63, tyg = tid >> 6;
    float acc[3][4] = {};
    for (int k0 = 0; k0 < DD; k0 += 32) {
#pragma unroll
        for (int i = 0; i < 2; ++i) {
            int idx = i * 256 + tid;
            int row = idx >> 5, kk = idx & 31;
            float v = s_v[row] ? Hprev[(size_t)s_e[row] * DD + k0 + kk] : 0.f;
            Hs[kk][row] = v;
        }
#pragma unroll
        for (int i = 0; i < 24; ++i) {
            int idx = i * 256 + tid;
            int nn = idx & 63, kk = (idx >> 6) & 31, s = idx >> 11;
            Bs[s][kk][nn] = Wh[(size_t)(k0 + kk) * ND3 + s * DD + c0 + nn];
        }
        __syncthreads();
#pragma unroll
        for (int kk = 0; kk < 32; ++kk) {
            float4 av = *(const float4*)&Hs[kk][tyg * 4];
            float b0 = Bs[0][kk][tx];
            float b1 = Bs[1][kk][tx];
            float b2 = Bs[2][kk][tx];
            acc[0][0] += av.x * b0; acc[0][1] += av.y * b0; acc[0][2] += av.z * b0; acc[0][3] += av.w * b0;
            acc[1][0] += av.x * b1; acc[1][1] += av.y * b1; acc[1][2] += av.z * b1; acc[1][3] += av.w * b1;
            acc[2][0] += av.x * b2; acc[2][1] += av.y * b2; acc[2][2] += av.z * b2; acc[2][3] += av.w * b2;
        }
        __syncthreads();
    }
#pragma unroll
    for (int j = 0; j < 4; ++j) {
        int lr = tyg * 4 + j;
        if (!s_v[lr]) continue;
        int e = s_e[lr], t = s_t[lr];
        int c = c0 + tx;
        float hr = acc[0][j] + bh[c];
        float hz = acc[1][j] + bh[DD + c];
        float hn = acc[2][j] + bh[2 * DD + c];
        float xr = xp[(size_t)t * ND3 + c];
        float xz = xp[(size_t)t * ND3 + DD + c];
        float xn = xp[(size_t)t * ND3 + 2 * DD + c];
        float hp = Hprev[(size_t)e * DD + c];
        float hnew = gru_out(xr, xz, xn, hr, hz, hn, hp);
        Hnext[(size_t)e * DD + c] = hnew;
        if (yf32) yf32[(size_t)t * DD + c] = hnew;
        else      ybf[(size_t)t * DD + c] = f2bf(hnew);
        if (t == TT - 1) finals[c] = hnew;
    }
}

// ---------------------------------------------------------------------------
// Cleanup: serially finish any episode with len > MAXIT (normally none).
// ---------------------------------------------------------------------------
__global__ __launch_bounds__(256)
void cleanup_kernel(const float* __restrict__ Hlast, const float* __restrict__ xp,
                    const float* __restrict__ Wh, const float* __restrict__ bh,
                    ushort* __restrict__ ybf, float* __restrict__ yf32,
                    float* __restrict__ finals, const int* __restrict__ g_start,
                    const int* __restrict__ g_len, const int* __restrict__ g_perm,
                    const int* __restrict__ g_nact)
{
    int Mt = g_nact[MAXIT];
    if (Mt == 0) return;
    __shared__ float h[DD];
    int tid = threadIdx.x;
    for (int r = blockIdx.x; r < Mt; r += gridDim.x) {
        int e = g_perm[r];
        int s0 = g_start[e];
        int L = g_len[e];
#pragma unroll
        for (int j = 0; j < 4; ++j) h[tid + j * 256] = Hlast[(size_t)e * DD + tid + j * 256];
        __syncthreads();
        for (int i = MAXIT; i < L; ++i) {
            int t = s0 + i;
            float hnew[4];
#pragma unroll
            for (int j = 0; j < 4; ++j) {
                int c = tid + j * 256;
                float hr = bh[c], hz = bh[DD + c], hn = bh[2 * DD + c];
                for (int k = 0; k < DD; ++k) {
                    float hv = h[k];
                    hr += hv * Wh[(size_t)k * ND3 + c];
                    hz += hv * Wh[(size_t)k * ND3 + DD + c];
                    hn += hv * Wh[(size_t)k * ND3 + 2 * DD + c];
                }
                float xr = xp[(size_t)t * ND3 + c];
                float xz = xp[(size_t)t * ND3 + DD + c];
                float xn = xp[(size_t)t * ND3 + 2 * DD + c];
                float hp = h[c];
                hnew[j] = gru_out(xr, xz, xn, hr, hz, hn, hp);
                if (yf32) yf32[(size_t)t * DD + c] = hnew[j];
                else      ybf[(size_t)t * DD + c] = f2bf(hnew[j]);
                if (t == TT - 1) finals[c] = hnew[j];
            }
            __syncthreads();
#pragma unroll
            for (int j = 0; j < 4; ++j) h[tid + j * 256] = hnew[j];
            __syncthreads();
        }
        __syncthreads();
    }
}

// ---------------------------------------------------------------------------
extern "C" void kernel_launch(void* const* d_in, const int* in_sizes, int n_in,
                              void* d_out, int out_size, void* d_ws, size_t ws_size,
                              hipStream_t stream)
{
    const float* x_in = (const float*)d_in[0];
    const int*   term = (const int*)d_in[1];
    const float* h0   = (const float*)d_in[2];
    const float* Wi   = (const float*)d_in[3];
    const float* Wh   = (const float*)d_in[4];
    const float* bh   = (const float*)d_in[5];
    float* out = (float*)d_out;

    float* wsf = (float*)d_ws;
    float*  xp  = wsf;                                   // TT*ND3 fp32
    float*  Hb0 = xp + (size_t)TT * ND3;                 // TT*DD fp32
    float*  Hb1 = Hb0 + (size_t)TT * DD;                 // TT*DD fp32
    ushort* Xbf = (ushort*)(Hb1 + (size_t)TT * DD);      // TT*DD bf16
    ushort* Yb0 = Xbf + (size_t)TT * DD;                 // TT*DD bf16
    ushort* Yb1 = Yb0 + (size_t)TT * DD;                 // TT*DD bf16
    ushort* WT  = Yb1 + (size_t)TT * DD;                 // ND3*DD bf16 (per-layer)
    int* ib      = (int*)(WT + (size_t)ND3 * DD);
    int* g_start = ib;
    int* g_len   = ib + TT;
    int* g_perm  = ib + 2 * TT;
    int* g_nact  = ib + 3 * TT;

    seg_kernel<<<1, 256, 0, stream>>>(term, g_start, g_len, g_perm, g_nact);
    cast_bf<<<(TT * DD / 4 + 255) / 256, 256, 0, stream>>>(x_in, Xbf, TT * DD);

    const ushort* Abf[4] = { Xbf, Yb0, Yb1, Yb0 };
    ushort*       Ybo[4] = { Yb0, Yb1, Yb0, nullptr };

    for (int l = 0; l < LL; ++l) {
        const float* Whl = Wh + (size_t)l * DD * ND3;
        const float* bhl = bh + (size_t)l * ND3;
        float* yf32 = (l == LL - 1) ? out : nullptr;
        ushort* ybf = Ybo[l];
        float* finals = out + (size_t)TT * DD + (size_t)l * DD;

        transcast<<<dim3(ND3 / 64, DD / 64), 256, 0, stream>>>(
            Wi + (size_t)l * DD * ND3, WT);
        gemm_mfma<<<dim3(ND3 / 128, TT / 128), 256, 0, stream>>>(Abf[l], WT, xp);

        it0_kernel<<<TT, 256, 0, stream>>>(xp, Whl, bhl, h0 + (size_t)l * DD, term,
                                           Hb0, ybf, yf32, finals,
                                           g_start, g_perm, g_nact);

        for (int it = 1; it < MAXIT; ++it) {
            float* Hp = (it & 1) ? Hb0 : Hb1;
            float* Hn = (it & 1) ? Hb1 : Hb0;
            int maxrows = TT / (it + 1);
            dim3 grd(DD / 64, (maxrows + 15) / 16);
            iter_kernel<<<grd, 256, 0, stream>>>(it, Hp, Hn, xp, Whl, bhl,
                                                 ybf, yf32, finals,
                                                 g_start, g_perm, g_nact);
        }

        float* Hlast = ((MAXIT - 1) & 1) ? Hb1 : Hb0;
        cleanup_kernel<<<64, 256, 0, stream>>>(Hlast, xp, Whl, bhl, ybf, yf32,
                                               finals, g_start, g_len, g_perm,
                                               g_nact);
    }
}

// Round 3
// 784.271 us; speedup vs baseline: 4.3554x; 3.3299x over previous
//
#include <hip/hip_runtime.h>

#define TT 2048
#define DD 1024
#define ND3 3072
#define LL 4
#define MAXIT 12

typedef float f32x4 __attribute__((ext_vector_type(4)));
typedef __bf16 bf16x8 __attribute__((ext_vector_type(8)));

__device__ __forceinline__ float sigmoidf_(float x) { return 1.f / (1.f + __expf(-x)); }

__device__ __forceinline__ float gru_out(float xr, float xz, float xn,
                                         float hr, float hz, float hn, float hp)
{
    float rg = sigmoidf_(xr + hr);
    float zg = sigmoidf_(xz + hz);
    float ng = tanhf(xn + rg * hn);
    return (1.f - zg) * ng + zg * hp;
}

__device__ __forceinline__ ushort f2bf(float x)
{
    unsigned u = __builtin_bit_cast(unsigned, x);
    return (ushort)((u + 0x7FFFu + ((u >> 16) & 1u)) >> 16);
}

__device__ __forceinline__ float bf2f(ushort u)
{
    return __builtin_bit_cast(float, ((unsigned)u) << 16);
}

__device__ __forceinline__ void gld_lds16(const void* g, void* l)
{
    __builtin_amdgcn_global_load_lds(
        (const __attribute__((address_space(1))) unsigned int*)g,
        (__attribute__((address_space(3))) unsigned int*)l, 16, 0, 0);
}

// ---------------------------------------------------------------------------
// Episode segmentation + counting sort (descending length). One block, parallel.
// g_nact[i] = #{episodes with len > i}, i=0..MAXIT (g_nact[0] = n_ep).
// ---------------------------------------------------------------------------
__global__ __launch_bounds__(256)
void seg_kernel(const int* __restrict__ term, int* __restrict__ g_start,
                int* __restrict__ g_len, int* __restrict__ g_perm,
                int* __restrict__ g_nact)
{
    __shared__ int s_start[TT + 1];
    __shared__ int s_len[TT];
    __shared__ int s_hist[TT + 1];
    __shared__ int s_base[TT + 1];
    __shared__ int s_p[256];
    __shared__ int s_wsum[33];
    __shared__ int s_n;
    int tid = threadIdx.x, lane = tid & 63, wv = tid >> 6;

    for (int i = tid; i <= TT; i += 256) s_hist[i] = 0;

    unsigned long long msk[8];
#pragma unroll
    for (int p = 0; p < 8; ++p) {
        int t = p * 256 + tid;
        int bit = (t == 0) || (term[t] != 0);
        unsigned long long m = __ballot(bit);
        msk[p] = m;
        if (lane == 0) s_wsum[p * 4 + wv] = __popcll(m);
    }
    __syncthreads();
    if (tid == 0) {
        int run = 0;
        for (int i = 0; i < 32; ++i) { int v = s_wsum[i]; s_wsum[i] = run; run += v; }
        s_n = run;
    }
    __syncthreads();
    int n = s_n;
#pragma unroll
    for (int p = 0; p < 8; ++p) {
        int t = p * 256 + tid;
        unsigned long long m = msk[p];
        if ((m >> lane) & 1ull) {
            int e = s_wsum[p * 4 + wv] + __popcll(m & ((1ull << lane) - 1ull));
            s_start[e] = t;
        }
    }
    if (tid == 0) s_start[n] = TT;
    __syncthreads();
    for (int e = tid; e < n; e += 256) {
        int L = s_start[e + 1] - s_start[e];
        s_len[e] = L;
        atomicAdd(&s_hist[L], 1);
    }
    __syncthreads();
    // suffix sums: s_base[L] = #{len > L} for L=1..TT (two-level scan)
    int lo = 8 * tid + 1;
    int p_i = 0;
#pragma unroll
    for (int j = 0; j < 8; ++j) p_i += s_hist[lo + j];
    s_p[tid] = p_i;
    __syncthreads();
    if (tid < 64) {
        int q0 = s_p[tid * 4], q1 = s_p[tid * 4 + 1], q2 = s_p[tid * 4 + 2], q3 = s_p[tid * 4 + 3];
        int q = q0 + q1 + q2 + q3;
        int acc = q;
        for (int off = 1; off < 64; off <<= 1) {
            int v = __shfl_down(acc, off);
            if (lane + off < 64) acc += v;
        }
        int ex = acc - q;   // sum over lanes > lane
        s_p[tid * 4 + 3] = ex;
        s_p[tid * 4 + 2] = ex + q3;
        s_p[tid * 4 + 1] = ex + q3 + q2;
        s_p[tid * 4 + 0] = ex + q3 + q2 + q1;
    }
    __syncthreads();
    int running = s_p[tid];
    for (int j = 7; j >= 0; --j) {
        s_base[lo + j] = running;
        running += s_hist[lo + j];
    }
    __syncthreads();
    if (tid == 0) g_nact[0] = n;
    if (tid >= 1 && tid <= MAXIT) g_nact[tid] = s_base[tid];
    __syncthreads();
    for (int e = tid; e < n; e += 256) {
        g_start[e] = s_start[e];
        int L = s_len[e];
        g_len[e] = L;
        int pos = atomicAdd(&s_base[L], 1);
        g_perm[pos] = e;
    }
}

// ---------------------------------------------------------------------------
// fp32 -> bf16 cast (vectorized), n multiple of 4
// ---------------------------------------------------------------------------
__global__ __launch_bounds__(256)
void cast_bf(const float* __restrict__ src, ushort* __restrict__ dst, int n)
{
    int base = (blockIdx.x * 256 + threadIdx.x) * 4;
    if (base < n) {
        float4 v = *(const float4*)(src + base);
        ushort4 o;
        o.x = f2bf(v.x); o.y = f2bf(v.y); o.z = f2bf(v.z); o.w = f2bf(v.w);
        *(ushort4*)(dst + base) = o;
    }
}

// ---------------------------------------------------------------------------
// Transpose + cast both weight matrices of a layer:
// z=0: Wi [DD][ND3] -> WT [ND3][DD] bf16 ; z=1: Wh -> WhT
// ---------------------------------------------------------------------------
__global__ __launch_bounds__(256)
void transcast2(const float* __restrict__ Wi_l, const float* __restrict__ Wh_l,
                ushort* __restrict__ WT, ushort* __restrict__ WhT)
{
    const float* src = blockIdx.z ? Wh_l : Wi_l;
    ushort* dst = blockIdx.z ? WhT : WT;
    __shared__ float tile[64][65];
    int tid = threadIdx.x;
    int n0 = blockIdx.x * 64, k0 = blockIdx.y * 64;
#pragma unroll
    for (int i = 0; i < 16; ++i) {
        int idx = i * 256 + tid;
        int r = idx >> 6, c = idx & 63;
        tile[r][c] = src[(size_t)(k0 + r) * ND3 + n0 + c];
    }
    __syncthreads();
#pragma unroll
    for (int i = 0; i < 8; ++i) {
        int idx = i * 256 + tid;
        int nr = idx >> 5, kp = idx & 31;
        float a = tile[kp * 2][nr], b = tile[kp * 2 + 1][nr];
        unsigned pa = (unsigned)f2bf(a) | ((unsigned)f2bf(b) << 16);
        *(unsigned*)&dst[(size_t)(n0 + nr) * DD + k0 + kp * 2] = pa;
    }
}

// ---------------------------------------------------------------------------
// Phase A GEMM (bf16 MFMA): C[2048][3072] = A[2048][1024] * BT[3072][1024]^T
// 128x128 tile, 4 waves (2x2), BK=32, global_load_lds staging, XOR k-slot
// swizzle. Output stored as bf16.
// ---------------------------------------------------------------------------
__global__ __launch_bounds__(256)
void gemm_mfma(const ushort* __restrict__ A, const ushort* __restrict__ BT,
               ushort* __restrict__ C)
{
    __shared__ __align__(16) ushort As[128 * 32];
    __shared__ __align__(16) ushort Bs[128 * 32];
    int tid = threadIdx.x, lane = tid & 63, wv = tid >> 6;
    int m0 = blockIdx.y * 128, n0 = blockIdx.x * 128;
    int wr = wv >> 1, wc = wv & 1;
    f32x4 acc[4][4] = {};

    int ci0 = tid, ci1 = 256 + tid;
    int r0s = ci0 >> 2, r1s = ci1 >> 2;
    int ss0 = (ci0 & 3) ^ ((r0s >> 1) & 3);
    int ss1 = (ci1 & 3) ^ ((r1s >> 1) & 3);
    const ushort* Ar0 = A + (size_t)(m0 + r0s) * DD + ss0 * 8;
    const ushort* Ar1 = A + (size_t)(m0 + r1s) * DD + ss1 * 8;
    const ushort* Br0 = BT + (size_t)(n0 + r0s) * DD + ss0 * 8;
    const ushort* Br1 = BT + (size_t)(n0 + r1s) * DD + ss1 * 8;

    int g = lane >> 4, fr = lane & 15;

    for (int k0 = 0; k0 < DD; k0 += 32) {
        gld_lds16(Ar0 + k0, (char*)As + wv * 1024);
        gld_lds16(Ar1 + k0, (char*)As + 4096 + wv * 1024);
        gld_lds16(Br0 + k0, (char*)Bs + wv * 1024);
        gld_lds16(Br1 + k0, (char*)Bs + 4096 + wv * 1024);
        __syncthreads();

        bf16x8 af[4], bb[4];
#pragma unroll
        for (int mi = 0; mi < 4; ++mi) {
            int row = wr * 64 + mi * 16 + fr;
            int slot = g ^ ((row >> 1) & 3);
            af[mi] = *(const bf16x8*)(As + row * 32 + slot * 8);
        }
#pragma unroll
        for (int ni = 0; ni < 4; ++ni) {
            int row = wc * 64 + ni * 16 + fr;
            int slot = g ^ ((row >> 1) & 3);
            bb[ni] = *(const bf16x8*)(Bs + row * 32 + slot * 8);
        }
#pragma unroll
        for (int mi = 0; mi < 4; ++mi)
#pragma unroll
            for (int ni = 0; ni < 4; ++ni)
                acc[mi][ni] = __builtin_amdgcn_mfma_f32_16x16x32_bf16(
                    af[mi], bb[ni], acc[mi][ni], 0, 0, 0);
        __syncthreads();
    }

    int orow = (lane >> 4) * 4, ocol = lane & 15;
#pragma unroll
    for (int mi = 0; mi < 4; ++mi)
#pragma unroll
        for (int ni = 0; ni < 4; ++ni)
#pragma unroll
            for (int r2 = 0; r2 < 4; ++r2)
                C[(size_t)(m0 + wr * 64 + mi * 16 + orow + r2) * ND3 +
                  n0 + wc * 64 + ni * 16 + ocol] = f2bf(acc[mi][ni][r2]);
}

// ---------------------------------------------------------------------------
// Iteration 0: h_in = 0 (or last_states for the t==0 episode).
// ---------------------------------------------------------------------------
__global__ __launch_bounds__(256)
void it0_kernel(const ushort* __restrict__ xp, const float* __restrict__ Wh,
                const float* __restrict__ bh, const float* __restrict__ h0g,
                const int* __restrict__ term, float* __restrict__ Hnext,
                ushort* __restrict__ Hbfn, ushort* __restrict__ ybf,
                float* __restrict__ yf32, float* __restrict__ finals,
                const int* __restrict__ g_start, const int* __restrict__ g_perm,
                const int* __restrict__ g_nact)
{
    int M = g_nact[0];
    int r = blockIdx.x;
    if (r >= M) return;
    int e = g_perm[r];
    int t = g_start[e];
    int tid = threadIdx.x;
    bool useh0 = (t == 0) && (term[0] == 0);
    __shared__ float h0s[DD];
    __shared__ int s_nz;
    if (tid == 0) s_nz = 0;
    __syncthreads();
    if (useh0) {
        int nz = 0;
#pragma unroll
        for (int j = 0; j < 4; ++j) {
            float v = h0g[tid + j * 256];
            h0s[tid + j * 256] = v;
            nz |= (v != 0.f) ? 1 : 0;
        }
        if (nz) atomicOr(&s_nz, 1);
    }
    __syncthreads();
    bool gemv = useh0 && (s_nz != 0);
#pragma unroll
    for (int j = 0; j < 4; ++j) {
        int c = tid + j * 256;
        float hr = bh[c], hz = bh[DD + c], hn = bh[2 * DD + c];
        if (gemv) {
            for (int k = 0; k < DD; ++k) {
                float hv = h0s[k];
                hr += hv * Wh[(size_t)k * ND3 + c];
                hz += hv * Wh[(size_t)k * ND3 + DD + c];
                hn += hv * Wh[(size_t)k * ND3 + 2 * DD + c];
            }
        }
        float hp = useh0 ? h0s[c] : 0.f;
        float xr = bf2f(xp[(size_t)t * ND3 + c]);
        float xz = bf2f(xp[(size_t)t * ND3 + DD + c]);
        float xn = bf2f(xp[(size_t)t * ND3 + 2 * DD + c]);
        float hnew = gru_out(xr, xz, xn, hr, hz, hn, hp);
        Hnext[(size_t)e * DD + c] = hnew;
        Hbfn[(size_t)e * DD + c] = f2bf(hnew);
        if (yf32) yf32[(size_t)t * DD + c] = hnew;
        else      ybf[(size_t)t * DD + c] = f2bf(hnew);
        if (t == TT - 1) finals[c] = hnew;
    }
}

// ---------------------------------------------------------------------------
// Iteration i>=1 (MFMA): hp_gemm = Hbf_active @ WhT^T, fused gates + update.
// 512 threads / 8 waves. Tile: 32 rows x (64 hcols x 3 gates). BK=32.
// Wave w: rows (w&1)*16, hcols (w>>1)*16; 3 MFMA per k-step (one per gate);
// all 3 gate values for (row,col) land in the same lane -> fused epilogue.
// ---------------------------------------------------------------------------
__global__ __launch_bounds__(512)
void iter_mfma(int it, const float* __restrict__ Hp, float* __restrict__ Hn,
               const ushort* __restrict__ Hbfp, ushort* __restrict__ Hbfn,
               const ushort* __restrict__ xp, const ushort* __restrict__ WhT,
               const float* __restrict__ bh, ushort* __restrict__ ybf,
               float* __restrict__ yf32, float* __restrict__ finals,
               const int* __restrict__ g_start, const int* __restrict__ g_perm,
               const int* __restrict__ g_nact)
{
    int M = g_nact[it];
    int r0 = blockIdx.y * 32;
    if (r0 >= M) return;
    int c0 = blockIdx.x * 64;
    __shared__ __align__(16) ushort As[32 * 32];     // 2 KB
    __shared__ __align__(16) ushort Bs[192 * 32];    // 12 KB
    __shared__ int s_e[32], s_t[32], s_v[32];
    int tid = threadIdx.x, lane = tid & 63, wv = tid >> 6;

    if (tid < 32) {
        int r = r0 + tid;
        int v = (r < M) ? 1 : 0;
        int e = v ? g_perm[r] : 0;
        s_e[tid] = e;
        s_v[tid] = v;
        s_t[tid] = v ? (g_start[e] + it) : 0;
    }

    // A staging source (chunks 0..127, waves 0-1): row = tid>>2, slot = tid&3
    const ushort* srcA = Hbfp;
    if (tid < 128) {
        int row = tid >> 2;
        int rr = r0 + row; if (rr > M - 1) rr = M - 1;
        int eA = g_perm[rr];
        int aslot = (tid & 3) ^ ((row >> 1) & 3);
        srcA = Hbfp + (size_t)eA * DD + aslot * 8;
    }
    // B pass0 (chunks 0..511): colj = tid>>2
    int colj0 = tid >> 2;
    int bs0 = (tid & 3) ^ ((colj0 >> 1) & 3);
    const ushort* srcB0 = WhT + (size_t)((colj0 >> 6) * DD + c0 + (colj0 & 63)) * DD + bs0 * 8;
    // B pass1 (chunks 512..767, waves 0-3): colj = 128 + tid>>2
    int colj1 = 128 + (tid >> 2);
    int bs1 = (tid & 3) ^ ((colj1 >> 1) & 3);
    const ushort* srcB1 = WhT + (size_t)((colj1 >> 6) * DD + c0 + (colj1 & 63)) * DD + bs1 * 8;

    int fr = lane & 15, g = lane >> 4;
    int rw = (wv & 1) * 16, hw = (wv >> 1) * 16;
    f32x4 acc[3] = {};

    for (int k0 = 0; k0 < DD; k0 += 32) {
        if (wv < 2) gld_lds16(srcA + k0, (char*)As + wv * 1024);
        gld_lds16(srcB0 + k0, (char*)Bs + wv * 1024);
        if (wv < 4) gld_lds16(srcB1 + k0, (char*)Bs + 8192 + wv * 1024);
        __syncthreads();

        int arow = rw + fr;
        bf16x8 af = *(const bf16x8*)(As + arow * 32 + (g ^ ((arow >> 1) & 3)) * 8);
#pragma unroll
        for (int f = 0; f < 3; ++f) {
            int cj = f * 64 + hw + fr;
            bf16x8 bb = *(const bf16x8*)(Bs + cj * 32 + (g ^ ((cj >> 1) & 3)) * 8);
            acc[f] = __builtin_amdgcn_mfma_f32_16x16x32_bf16(af, bb, acc[f], 0, 0, 0);
        }
        __syncthreads();
    }

    int col = c0 + hw + fr;
#pragma unroll
    for (int r2 = 0; r2 < 4; ++r2) {
        int row = rw + g * 4 + r2;
        if (!s_v[row]) continue;
        int e = s_e[row], t = s_t[row];
        float hr = acc[0][r2] + bh[col];
        float hz = acc[1][r2] + bh[DD + col];
        float hn = acc[2][r2] + bh[2 * DD + col];
        float xr = bf2f(xp[(size_t)t * ND3 + col]);
        float xz = bf2f(xp[(size_t)t * ND3 + DD + col]);
        float xn = bf2f(xp[(size_t)t * ND3 + 2 * DD + col]);
        float hp = Hp[(size_t)e * DD + col];
        float hnew = gru_out(xr, xz, xn, hr, hz, hn, hp);
        Hn[(size_t)e * DD + col] = hnew;
        Hbfn[(size_t)e * DD + col] = f2bf(hnew);
        if (yf32) yf32[(size_t)t * DD + col] = hnew;
        else      ybf[(size_t)t * DD + col] = f2bf(hnew);
        if (t == TT - 1) finals[col] = hnew;
    }
}

// ---------------------------------------------------------------------------
// Cleanup: serially finish any episode with len > MAXIT (normally none/few).
// ---------------------------------------------------------------------------
__global__ __launch_bounds__(256)
void cleanup_kernel(const float* __restrict__ Hlast, const ushort* __restrict__ xp,
                    const float* __restrict__ Wh, const float* __restrict__ bh,
                    ushort* __restrict__ ybf, float* __restrict__ yf32,
                    float* __restrict__ finals, const int* __restrict__ g_start,
                    const int* __restrict__ g_len, const int* __restrict__ g_perm,
                    const int* __restrict__ g_nact)
{
    int Mt = g_nact[MAXIT];
    if (Mt == 0) return;
    __shared__ float h[DD];
    int tid = threadIdx.x;
    for (int r = blockIdx.x; r < Mt; r += gridDim.x) {
        int e = g_perm[r];
        int s0 = g_start[e];
        int L = g_len[e];
#pragma unroll
        for (int j = 0; j < 4; ++j) h[tid + j * 256] = Hlast[(size_t)e * DD + tid + j * 256];
        __syncthreads();
        for (int i = MAXIT; i < L; ++i) {
            int t = s0 + i;
            float hnew[4];
#pragma unroll
            for (int j = 0; j < 4; ++j) {
                int c = tid + j * 256;
                float hr = bh[c], hz = bh[DD + c], hn = bh[2 * DD + c];
                for (int k = 0; k < DD; ++k) {
                    float hv = h[k];
                    hr += hv * Wh[(size_t)k * ND3 + c];
                    hz += hv * Wh[(size_t)k * ND3 + DD + c];
                    hn += hv * Wh[(size_t)k * ND3 + 2 * DD + c];
                }
                float xr = bf2f(xp[(size_t)t * ND3 + c]);
                float xz = bf2f(xp[(size_t)t * ND3 + DD + c]);
                float xn = bf2f(xp[(size_t)t * ND3 + 2 * DD + c]);
                float hp = h[c];
                hnew[j] = gru_out(xr, xz, xn, hr, hz, hn, hp);
                if (yf32) yf32[(size_t)t * DD + c] = hnew[j];
                else      ybf[(size_t)t * DD + c] = f2bf(hnew[j]);
                if (t == TT - 1) finals[c] = hnew[j];
            }
            __syncthreads();
#pragma unroll
            for (int j = 0; j < 4; ++j) h[tid + j * 256] = hnew[j];
            __syncthreads();
        }
        __syncthreads();
    }
}

// ---------------------------------------------------------------------------
extern "C" void kernel_launch(void* const* d_in, const int* in_sizes, int n_in,
                              void* d_out, int out_size, void* d_ws, size_t ws_size,
                              hipStream_t stream)
{
    const float* x_in = (const float*)d_in[0];
    const int*   term = (const int*)d_in[1];
    const float* h0   = (const float*)d_in[2];
    const float* Wi   = (const float*)d_in[3];
    const float* Wh   = (const float*)d_in[4];
    const float* bh   = (const float*)d_in[5];
    float* out = (float*)d_out;

    ushort* xp   = (ushort*)d_ws;                    // TT*ND3 bf16
    float*  Hb0  = (float*)(xp + (size_t)TT * ND3);  // TT*DD fp32
    float*  Hb1  = Hb0 + (size_t)TT * DD;            // TT*DD fp32
    ushort* Hbf0 = (ushort*)(Hb1 + (size_t)TT * DD); // TT*DD bf16
    ushort* Hbf1 = Hbf0 + (size_t)TT * DD;           // TT*DD bf16
    ushort* Xbf  = Hbf1 + (size_t)TT * DD;           // TT*DD bf16
    ushort* Yb0  = Xbf + (size_t)TT * DD;            // TT*DD bf16
    ushort* Yb1  = Yb0 + (size_t)TT * DD;            // TT*DD bf16
    ushort* WT   = Yb1 + (size_t)TT * DD;            // ND3*DD bf16
    ushort* WhT  = WT + (size_t)ND3 * DD;            // ND3*DD bf16
    int* ib      = (int*)(WhT + (size_t)ND3 * DD);
    int* g_start = ib;
    int* g_len   = ib + TT;
    int* g_perm  = ib + 2 * TT;
    int* g_nact  = ib + 3 * TT;

    seg_kernel<<<1, 256, 0, stream>>>(term, g_start, g_len, g_perm, g_nact);
    cast_bf<<<(TT * DD / 4 + 255) / 256, 256, 0, stream>>>(x_in, Xbf, TT * DD);

    const ushort* Abf[4] = { Xbf, Yb0, Yb1, Yb0 };
    ushort*       Ybo[4] = { Yb0, Yb1, Yb0, nullptr };

    for (int l = 0; l < LL; ++l) {
        const float* Whl = Wh + (size_t)l * DD * ND3;
        const float* bhl = bh + (size_t)l * ND3;
        float* yf32 = (l == LL - 1) ? out : nullptr;
        ushort* ybf = Ybo[l];
        float* finals = out + (size_t)TT * DD + (size_t)l * DD;

        transcast2<<<dim3(ND3 / 64, DD / 64, 2), 256, 0, stream>>>(
            Wi + (size_t)l * DD * ND3, Whl, WT, WhT);
        gemm_mfma<<<dim3(ND3 / 128, TT / 128), 256, 0, stream>>>(Abf[l], WT, xp);

        it0_kernel<<<TT, 256, 0, stream>>>(xp, Whl, bhl, h0 + (size_t)l * DD, term,
                                           Hb0, Hbf0, ybf, yf32, finals,
                                           g_start, g_perm, g_nact);

        for (int it = 1; it < MAXIT; ++it) {
            float*  Hp   = (it & 1) ? Hb0 : Hb1;
            float*  Hn   = (it & 1) ? Hb1 : Hb0;
            ushort* Hbfp = (it & 1) ? Hbf0 : Hbf1;
            ushort* Hbfn = (it & 1) ? Hbf1 : Hbf0;
            int maxrows = TT / (it + 1);
            dim3 grd(DD / 64, (maxrows + 31) / 32);
            iter_mfma<<<grd, 512, 0, stream>>>(it, Hp, Hn, Hbfp, Hbfn, xp, WhT,
                                               bhl, ybf, yf32, finals,
                                               g_start, g_perm, g_nact);
        }

        float* Hlast = ((MAXIT - 1) & 1) ? Hb1 : Hb0;
        cleanup_kernel<<<64, 256, 0, stream>>>(Hlast, xp, Whl, bhl, ybf, yf32,
                                               finals, g_start, g_len, g_perm,
                                               g_nact);
    }
}